// Round 1
// baseline (2780.130 us; speedup 1.0000x reference)
//
#include <hip/hip_runtime.h>
#include <math.h>

#define F_IN 128
#define F_HID 64
#define F_OUT 40
#define BN_EPS 1e-5f

// ---- degree via atomic count (self-loop +1 added in k_dinv) ----
__global__ void k_deg(const int* __restrict__ col, int E, float* __restrict__ deg) {
    int e = blockIdx.x * blockDim.x + threadIdx.x;
    if (e < E) atomicAdd(deg + col[e], 1.0f);
}

__global__ void k_dinv(float* __restrict__ deg, int n) {
    int i = blockIdx.x * blockDim.x + threadIdx.x;
    if (i < n) deg[i] = rsqrtf(deg[i] + 1.0f);  // deg>=1 always (self-loop)
}

// ---- h1 = BN(x) @ W1 ; one wave per node, W1 in LDS, x row via shuffle ----
__global__ __launch_bounds__(256) void k_gemm1(
        const float* __restrict__ x, const float* __restrict__ gamma,
        const float* __restrict__ beta, const float* __restrict__ mean,
        const float* __restrict__ var, const float* __restrict__ W1,
        float* __restrict__ h1, int n) {
    __shared__ float sW[F_IN * F_HID];  // 32 KB
    for (int i = threadIdx.x; i < F_IN * F_HID; i += 256) sW[i] = W1[i];
    __syncthreads();
    int lane = threadIdx.x & 63;
    int wv   = threadIdx.x >> 6;
    // BN as affine: xn = x*s + t
    float s0 = rsqrtf(var[lane] + BN_EPS) * gamma[lane];
    float t0 = beta[lane] - mean[lane] * s0;
    float s1 = rsqrtf(var[64 + lane] + BN_EPS) * gamma[64 + lane];
    float t1 = beta[64 + lane] - mean[64 + lane] * s1;
    int stride = gridDim.x * 4;
    for (int node = blockIdx.x * 4 + wv; node < n; node += stride) {
        float x0 = x[(long)node * F_IN + lane] * s0 + t0;
        float x1 = x[(long)node * F_IN + 64 + lane] * s1 + t1;
        float acc = 0.f;
        #pragma unroll
        for (int k = 0; k < 64; ++k) {
            acc += __shfl(x0, k) * sW[k * F_HID + lane];
            acc += __shfl(x1, k) * sW[(64 + k) * F_HID + lane];
        }
        h1[(long)node * F_HID + lane] = acc;
    }
}

// ---- conv1 scatter: 16 threads/edge, 4 feats each ----
__global__ void k_scatter1(const int* __restrict__ row, const int* __restrict__ col,
                           const float* __restrict__ dinv, const float* __restrict__ h1,
                           float* __restrict__ agg, int E) {
    long tid = (long)blockIdx.x * blockDim.x + threadIdx.x;
    int e  = (int)(tid >> 4);
    int fg = (int)(tid & 15) << 2;
    if (e >= E) return;
    int r = row[e], c = col[e];
    float w = dinv[r] * dinv[c];
    float4 v = *(const float4*)(h1 + (long)r * F_HID + fg);
    float* dst = agg + (long)c * F_HID + fg;
    atomicAdd(dst + 0, v.x * w);
    atomicAdd(dst + 1, v.y * w);
    atomicAdd(dst + 2, v.z * w);
    atomicAdd(dst + 3, v.w * w);
}

// ---- h = relu(agg1 + dinv^2 * h1 + b1), in place into agg1 ----
__global__ void k_post1(float* __restrict__ agg, const float* __restrict__ h1,
                        const float* __restrict__ dinv, const float* __restrict__ b1, int n) {
    long i = (long)blockIdx.x * blockDim.x + threadIdx.x;
    if (i >= (long)n * F_HID) return;
    int node = (int)(i >> 6), f = (int)(i & 63);
    float d = dinv[node];
    float v = agg[i] + d * d * h1[i] + b1[f];
    agg[i] = fmaxf(v, 0.f);
}

// ---- h2 = h @ W2 ; one wave per node ----
__global__ __launch_bounds__(256) void k_gemm2(
        const float* __restrict__ h, const float* __restrict__ W2,
        float* __restrict__ h2, int n) {
    __shared__ float sW[F_HID * F_OUT + 64];  // +64 pad: lanes >=40 read junk, discarded
    for (int i = threadIdx.x; i < F_HID * F_OUT + 64; i += 256)
        sW[i] = (i < F_HID * F_OUT) ? W2[i] : 0.f;
    __syncthreads();
    int lane = threadIdx.x & 63;
    int wv   = threadIdx.x >> 6;
    int stride = gridDim.x * 4;
    for (int node = blockIdx.x * 4 + wv; node < n; node += stride) {
        float hv = h[(long)node * F_HID + lane];
        float acc = 0.f;
        #pragma unroll
        for (int k = 0; k < 64; ++k)
            acc += __shfl(hv, k) * sW[k * F_OUT + lane];
        if (lane < F_OUT) h2[(long)node * F_OUT + lane] = acc;
    }
}

// ---- conv2 scatter: 10 threads/edge, 4 feats each, accumulate into d_out ----
__global__ void k_scatter2(const int* __restrict__ row, const int* __restrict__ col,
                           const float* __restrict__ dinv, const float* __restrict__ h2,
                           float* __restrict__ out, int E) {
    long tid = (long)blockIdx.x * blockDim.x + threadIdx.x;
    int e  = (int)(tid / 10);
    int fg = (int)(tid % 10) * 4;
    if (e >= E) return;
    int r = row[e], c = col[e];
    float w = dinv[r] * dinv[c];
    float4 v = *(const float4*)(h2 + (long)r * F_OUT + fg);
    float* dst = out + (long)c * F_OUT + fg;
    atomicAdd(dst + 0, v.x * w);
    atomicAdd(dst + 1, v.y * w);
    atomicAdd(dst + 2, v.z * w);
    atomicAdd(dst + 3, v.w * w);
}

// ---- out = log_softmax(out + dinv^2*h2 + b2), one wave per node ----
__global__ __launch_bounds__(256) void k_post2(float* __restrict__ out,
                        const float* __restrict__ h2, const float* __restrict__ dinv,
                        const float* __restrict__ b2, int n) {
    int t = blockIdx.x * 256 + threadIdx.x;
    int node = t >> 6, lane = t & 63;
    if (node >= n) return;
    float d = dinv[node];
    long base = (long)node * F_OUT;
    float v = -INFINITY;
    if (lane < F_OUT) v = out[base + lane] + d * d * h2[base + lane] + b2[lane];
    float m = v;
    #pragma unroll
    for (int o = 32; o > 0; o >>= 1) m = fmaxf(m, __shfl_xor(m, o));
    float ex = (lane < F_OUT) ? expf(v - m) : 0.f;
    float s = ex;
    #pragma unroll
    for (int o = 32; o > 0; o >>= 1) s += __shfl_xor(s, o);
    float lse = logf(s) + m;
    if (lane < F_OUT) out[base + lane] = v - lse;
}

extern "C" void kernel_launch(void* const* d_in, const int* in_sizes, int n_in,
                              void* d_out, int out_size, void* d_ws, size_t ws_size,
                              hipStream_t stream) {
    const float* x     = (const float*)d_in[0];
    const int*   ei    = (const int*)d_in[1];
    const float* gamma = (const float*)d_in[2];
    const float* beta  = (const float*)d_in[3];
    const float* rmean = (const float*)d_in[4];
    const float* rvar  = (const float*)d_in[5];
    const float* W1    = (const float*)d_in[6];
    const float* b1    = (const float*)d_in[7];
    const float* W2    = (const float*)d_in[8];
    const float* b2    = (const float*)d_in[9];
    float* out = (float*)d_out;

    int n = in_sizes[0] / F_IN;
    int E = in_sizes[1] / 2;
    const int* row = ei;       // edge_index[0] = source
    const int* col = ei + E;   // edge_index[1] = target

    float* ws   = (float*)d_ws;
    float* dinv = ws;                           // n floats (deg then dinv)
    float* h1   = ws + n;                       // n*64 (reused as h2: n*40)
    float* agg1 = h1 + (size_t)n * F_HID;       // n*64 (becomes h in place)
    float* h2   = h1;

    hipMemsetAsync(dinv, 0, (size_t)n * sizeof(float), stream);
    hipMemsetAsync(agg1, 0, (size_t)n * F_HID * sizeof(float), stream);
    hipMemsetAsync(out,  0, (size_t)out_size * sizeof(float), stream);

    k_deg <<<(E + 255) / 256, 256, 0, stream>>>(col, E, dinv);
    k_dinv<<<(n + 255) / 256, 256, 0, stream>>>(dinv, n);
    k_gemm1<<<1024, 256, 0, stream>>>(x, gamma, beta, rmean, rvar, W1, h1, n);

    long t1 = (long)E * 16;
    k_scatter1<<<(int)((t1 + 255) / 256), 256, 0, stream>>>(row, col, dinv, h1, agg1, E);
    long p1 = (long)n * F_HID;
    k_post1<<<(int)((p1 + 255) / 256), 256, 0, stream>>>(agg1, h1, dinv, b1, n);

    k_gemm2<<<1024, 256, 0, stream>>>(agg1, W2, h2, n);
    long t2 = (long)E * 10;
    k_scatter2<<<(int)((t2 + 255) / 256), 256, 0, stream>>>(row, col, dinv, h2, out, E);
    k_post2<<<(n * 64 + 255) / 256, 256, 0, stream>>>(out, h2, dinv, b2, n);
}

// Round 2
// 845.941 us; speedup vs baseline: 3.2864x; 3.2864x over previous
//
#include <hip/hip_runtime.h>
#include <math.h>

#define F_IN 128
#define F_HID 64
#define F_OUT 40
#define BN_EPS 1e-5f

// ---- in-degree histogram (int atomics) ----
__global__ void k_deg(const int* __restrict__ col, int E, int* __restrict__ deg) {
    int e = blockIdx.x * blockDim.x + threadIdx.x;
    if (e < E) atomicAdd(deg + col[e], 1);
}

// ---- segment allocation via global cursor; also dinv = rsqrt(deg+1) ----
__global__ void k_offsets(const int* __restrict__ deg, int* __restrict__ off,
                          int* __restrict__ fill, float* __restrict__ dinv,
                          int* __restrict__ cursor, int n) {
    int i = blockIdx.x * blockDim.x + threadIdx.x;
    if (i >= n) return;
    int d = deg[i];
    int base = atomicAdd(cursor, d);
    off[i] = base;
    fill[i] = base;
    dinv[i] = rsqrtf((float)d + 1.0f);  // +1 self-loop
}

// ---- scatter edge payload {src, dinv[src]} into CSR slots ----
__global__ void k_edges(const int* __restrict__ row, const int* __restrict__ col,
                        const float* __restrict__ dinv, int* __restrict__ fill,
                        int2* __restrict__ pairs, int E) {
    int e = blockIdx.x * blockDim.x + threadIdx.x;
    if (e >= E) return;
    int r = row[e], c = col[e];
    int pos = atomicAdd(fill + c, 1);
    int2 p;
    p.x = r;
    p.y = __float_as_int(dinv[r]);
    pairs[pos] = p;
}

// ---- h1 = BN(x) @ W1 ; one wave per node, W1 in LDS, x row via shuffle ----
__global__ __launch_bounds__(256) void k_gemm1(
        const float* __restrict__ x, const float* __restrict__ gamma,
        const float* __restrict__ beta, const float* __restrict__ mean,
        const float* __restrict__ var, const float* __restrict__ W1,
        float* __restrict__ h1, int n) {
    __shared__ float sW[F_IN * F_HID];  // 32 KB
    for (int i = threadIdx.x; i < F_IN * F_HID; i += 256) sW[i] = W1[i];
    __syncthreads();
    int lane = threadIdx.x & 63;
    int wv   = threadIdx.x >> 6;
    float s0 = rsqrtf(var[lane] + BN_EPS) * gamma[lane];
    float t0 = beta[lane] - mean[lane] * s0;
    float s1 = rsqrtf(var[64 + lane] + BN_EPS) * gamma[64 + lane];
    float t1 = beta[64 + lane] - mean[64 + lane] * s1;
    int stride = gridDim.x * 4;
    for (int node = blockIdx.x * 4 + wv; node < n; node += stride) {
        float x0 = x[(long)node * F_IN + lane] * s0 + t0;
        float x1 = x[(long)node * F_IN + 64 + lane] * s1 + t1;
        float acc = 0.f;
        #pragma unroll
        for (int k = 0; k < 64; ++k) {
            acc += __shfl(x0, k) * sW[k * F_HID + lane];
            acc += __shfl(x1, k) * sW[(64 + k) * F_HID + lane];
        }
        h1[(long)node * F_HID + lane] = acc;
    }
}

// ---- conv1 gather + self-loop + bias + relu + GEMM2 fused ----
// wave per node; lane = feature of h (64); W2 staged in LDS.
__global__ __launch_bounds__(256) void k_conv1(
        const float* __restrict__ h1, const int2* __restrict__ pairs,
        const int* __restrict__ off, const int* __restrict__ endp,
        const float* __restrict__ dinv, const float* __restrict__ b1,
        const float* __restrict__ W2, float* __restrict__ h2, int n) {
    __shared__ float sW[F_HID * F_OUT + 24];  // 2584: lanes>=40 read junk, discarded
    for (int i = threadIdx.x; i < F_HID * F_OUT + 24; i += 256)
        sW[i] = (i < F_HID * F_OUT) ? W2[i] : 0.f;
    __syncthreads();
    int lane = threadIdx.x & 63;
    int node = blockIdx.x * 4 + (threadIdx.x >> 6);
    if (node >= n) return;
    int s = off[node], e = endp[node];
    float acc = 0.f;
    for (int j = s; j < e; ++j) {
        int2 p = pairs[j];                        // wave-broadcast 8B load
        float v = h1[(long)p.x * F_HID + lane];   // coalesced 256B row
        acc = fmaf(__int_as_float(p.y), v, acc);
    }
    float d = dinv[node];
    float self = h1[(long)node * F_HID + lane];
    float hr = fmaxf(d * acc + d * d * self + b1[lane], 0.f);
    // fused GEMM2: h2 = hr @ W2
    float acc2 = 0.f;
    #pragma unroll
    for (int k = 0; k < F_HID; ++k)
        acc2 = fmaf(__shfl(hr, k), sW[k * F_OUT + lane], acc2);
    if (lane < F_OUT) h2[(long)node * F_OUT + lane] = acc2;
}

// ---- conv2 gather + self-loop + bias + log_softmax fused ----
__global__ __launch_bounds__(256) void k_conv2(
        const float* __restrict__ h2, const int2* __restrict__ pairs,
        const int* __restrict__ off, const int* __restrict__ endp,
        const float* __restrict__ dinv, const float* __restrict__ b2,
        float* __restrict__ out, int n) {
    int lane = threadIdx.x & 63;
    int node = blockIdx.x * 4 + (threadIdx.x >> 6);
    if (node >= n) return;
    int s = off[node], e = endp[node];
    float acc = 0.f;
    for (int j = s; j < e; ++j) {
        int2 p = pairs[j];
        float v = (lane < F_OUT) ? h2[(long)p.x * F_OUT + lane] : 0.f;
        acc = fmaf(__int_as_float(p.y), v, acc);
    }
    float d = dinv[node];
    float v = -INFINITY;
    if (lane < F_OUT) {
        float self = h2[(long)node * F_OUT + lane];
        v = d * acc + d * d * self + b2[lane];
    }
    float m = v;
    #pragma unroll
    for (int o = 32; o > 0; o >>= 1) m = fmaxf(m, __shfl_xor(m, o));
    float ex = (lane < F_OUT) ? expf(v - m) : 0.f;
    float ssum = ex;
    #pragma unroll
    for (int o = 32; o > 0; o >>= 1) ssum += __shfl_xor(ssum, o);
    float lse = logf(ssum) + m;
    if (lane < F_OUT) out[(long)node * F_OUT + lane] = v - lse;
}

extern "C" void kernel_launch(void* const* d_in, const int* in_sizes, int n_in,
                              void* d_out, int out_size, void* d_ws, size_t ws_size,
                              hipStream_t stream) {
    const float* x     = (const float*)d_in[0];
    const int*   ei    = (const int*)d_in[1];
    const float* gamma = (const float*)d_in[2];
    const float* beta  = (const float*)d_in[3];
    const float* rmean = (const float*)d_in[4];
    const float* rvar  = (const float*)d_in[5];
    const float* W1    = (const float*)d_in[6];
    const float* b1    = (const float*)d_in[7];
    const float* W2    = (const float*)d_in[8];
    const float* b2    = (const float*)d_in[9];
    float* out = (float*)d_out;

    int n = in_sizes[0] / F_IN;
    int E = in_sizes[1] / 2;
    const int* row = ei;       // edge_index[0] = source
    const int* col = ei + E;   // edge_index[1] = target

    // workspace layout (8B-aligned where needed): 4n+2 ints, then pairs, h1, h2
    int*   deg    = (int*)d_ws;
    int*   off    = deg + n;
    int*   fill   = off + n;
    float* dinv   = (float*)(fill + n);
    int*   cursor = (int*)(dinv + n);          // 2 ints (alignment)
    int2*  pairs  = (int2*)(cursor + 2);       // E pairs, 8B aligned
    float* h1     = (float*)(pairs + E);       // n*64
    float* h2     = h1 + (size_t)n * F_HID;    // n*40

    hipMemsetAsync(deg, 0, (size_t)n * sizeof(int), stream);
    hipMemsetAsync(cursor, 0, 2 * sizeof(int), stream);

    k_deg    <<<(E + 255) / 256, 256, 0, stream>>>(col, E, deg);
    k_offsets<<<(n + 255) / 256, 256, 0, stream>>>(deg, off, fill, dinv, cursor, n);
    k_edges  <<<(E + 255) / 256, 256, 0, stream>>>(row, col, dinv, fill, pairs, E);
    // after k_edges, fill[i] == off[i] + deg[i] == segment end

    k_gemm1<<<1024, 256, 0, stream>>>(x, gamma, beta, rmean, rvar, W1, h1, n);
    k_conv1<<<(n + 3) / 4, 256, 0, stream>>>(h1, pairs, off, fill, dinv, b1, W2, h2, n);
    k_conv2<<<(n + 3) / 4, 256, 0, stream>>>(h2, pairs, off, fill, dinv, b2, out, n);
}

// Round 3
// 619.895 us; speedup vs baseline: 4.4848x; 1.3647x over previous
//
#include <hip/hip_runtime.h>
#include <hip/hip_bf16.h>
#include <math.h>

#define F_IN 128
#define F_HID 64
#define F_OUT 40
#define BN_EPS 1e-5f

// ---- in-degree histogram (int atomics) ----
__global__ void k_deg(const int* __restrict__ col, int E, int* __restrict__ deg) {
    int e = blockIdx.x * blockDim.x + threadIdx.x;
    if (e < E) atomicAdd(deg + col[e], 1);
}

// ---- segment allocation via global cursor; also dinv = rsqrt(deg+1) ----
__global__ void k_offsets(const int* __restrict__ deg, int* __restrict__ off,
                          int* __restrict__ fill, float* __restrict__ dinv,
                          int* __restrict__ cursor, int n) {
    int i = blockIdx.x * blockDim.x + threadIdx.x;
    if (i >= n) return;
    int d = deg[i];
    int base = atomicAdd(cursor, d);
    off[i] = base;
    fill[i] = base;
    dinv[i] = rsqrtf((float)d + 1.0f);  // +1 self-loop
}

// ---- scatter edge payload {src, dinv[src]} into CSR slots ----
__global__ void k_edges(const int* __restrict__ row, const int* __restrict__ col,
                        const float* __restrict__ dinv, int* __restrict__ fill,
                        int2* __restrict__ pairs, int E) {
    int e = blockIdx.x * blockDim.x + threadIdx.x;
    if (e >= E) return;
    int r = row[e], c = col[e];
    int pos = atomicAdd(fill + c, 1);
    int2 p;
    p.x = r;
    p.y = __float_as_int(dinv[r]);
    pairs[pos] = p;
}

// ---- h1 = BN(x) @ W1, scalar-W structure: lane = node, W row as s_load ----
// block = 64 threads = 1 wave = 64-node tile. LDS holds x-tile [64][129].
__global__ __launch_bounds__(64) void k_gemm1(
        const float* __restrict__ x, const float* __restrict__ gamma,
        const float* __restrict__ beta, const float* __restrict__ mean,
        const float* __restrict__ var, const float* __restrict__ W1,
        __hip_bfloat16* __restrict__ h1b, int n) {
    __shared__ float xl[64 * 129];              // 33 KB; pad 129 -> conflict-free reads
    __shared__ __align__(16) float bs[F_IN];
    __shared__ __align__(16) float bt[F_IN];
    int lane = threadIdx.x;
    for (int f = lane; f < F_IN; f += 64) {
        float s = rsqrtf(var[f] + BN_EPS) * gamma[f];
        bs[f] = s;
        bt[f] = beta[f] - mean[f] * s;
    }
    __syncthreads();
    int nb = blockIdx.x * 64;
    int tn = lane >> 5;            // 0/1: which of 2 nodes this instr covers
    int f4 = (lane & 31) * 4;
    for (int it = 0; it < 32; ++it) {
        int r = it * 2 + tn;       // node within tile
        int node = nb + r;
        float4 v = make_float4(0.f, 0.f, 0.f, 0.f);
        if (node < n) v = *(const float4*)(x + (long)node * F_IN + f4);
        float4 s4 = *(const float4*)(bs + f4);
        float4 t4 = *(const float4*)(bt + f4);
        int base = r * 129 + f4;
        xl[base + 0] = v.x * s4.x + t4.x;
        xl[base + 1] = v.y * s4.y + t4.y;
        xl[base + 2] = v.z * s4.z + t4.z;
        xl[base + 3] = v.w * s4.w + t4.w;
    }
    __syncthreads();
    float acc[F_HID];
    #pragma unroll
    for (int f = 0; f < F_HID; ++f) acc[f] = 0.f;
    for (int k = 0; k < F_IN; ++k) {
        float xv = xl[lane * 129 + k];          // conflict-free (129%32==1)
        const float* wr = W1 + k * F_HID;       // uniform -> s_load operands
        #pragma unroll
        for (int f = 0; f < F_HID; ++f) acc[f] = fmaf(xv, wr[f], acc[f]);
    }
    int node = nb + lane;
    if (node < n) {
        __hip_bfloat16* dst = h1b + (long)node * F_HID;
        #pragma unroll
        for (int f = 0; f < F_HID; f += 2) {
            __hip_bfloat162 pr;
            pr.x = __float2bfloat16(acc[f]);
            pr.y = __float2bfloat16(acc[f + 1]);
            *(__hip_bfloat162*)(dst + f) = pr;
        }
    }
}

// ---- conv1 gather (bf16, MLP-4) + self + bias + relu + GEMM2 (W2 in VGPRs) ----
__global__ __launch_bounds__(256) void k_conv1(
        const __hip_bfloat16* __restrict__ h1b, const int2* __restrict__ pairs,
        const int* __restrict__ off, const int* __restrict__ endp,
        const float* __restrict__ dinv, const float* __restrict__ b1,
        const float* __restrict__ W2, __hip_bfloat16* __restrict__ h2b, int n) {
    int lane = threadIdx.x & 63;
    int node = blockIdx.x * 4 + (threadIdx.x >> 6);
    if (node >= n) return;
    // W2 column for this lane's output feature, literal-indexed regs
    float wreg[F_HID];
    #pragma unroll
    for (int k = 0; k < F_HID; ++k)
        wreg[k] = (lane < F_OUT) ? W2[k * F_OUT + lane] : 0.f;

    int s = off[node], e = endp[node];
    float acc = 0.f;
    int j = s;
    while (j < e) {
        int cnt = e - j;
        if (cnt > 64) cnt = 64;
        int2 p = make_int2(0, 0);
        if (lane < cnt) p = pairs[j + lane];    // one coalesced 8B load / 64 edges
        float pw = __int_as_float(p.y);
        int i = 0;
        for (; i + 4 <= cnt; i += 4) {          // 4 independent gathers in flight
            int s0 = __shfl(p.x, i),     s1 = __shfl(p.x, i + 1);
            int s2 = __shfl(p.x, i + 2), s3 = __shfl(p.x, i + 3);
            float w0 = __shfl(pw, i),     w1 = __shfl(pw, i + 1);
            float w2 = __shfl(pw, i + 2), w3 = __shfl(pw, i + 3);
            float v0 = __bfloat162float(h1b[(long)s0 * F_HID + lane]);
            float v1 = __bfloat162float(h1b[(long)s1 * F_HID + lane]);
            float v2 = __bfloat162float(h1b[(long)s2 * F_HID + lane]);
            float v3 = __bfloat162float(h1b[(long)s3 * F_HID + lane]);
            acc = fmaf(w0, v0, acc);
            acc = fmaf(w1, v1, acc);
            acc = fmaf(w2, v2, acc);
            acc = fmaf(w3, v3, acc);
        }
        for (; i < cnt; ++i) {
            int sv = __shfl(p.x, i);
            float wv = __shfl(pw, i);
            acc = fmaf(wv, __bfloat162float(h1b[(long)sv * F_HID + lane]), acc);
        }
        j += cnt;
    }
    float d = dinv[node];
    float self = __bfloat162float(h1b[(long)node * F_HID + lane]);
    float hr = fmaxf(d * acc + d * d * self + b1[lane], 0.f);
    // fused GEMM2: acc2[fo=lane] = sum_k hr(k) * W2[k][fo]
    float acc2 = 0.f;
    #pragma unroll
    for (int k = 0; k < F_HID; ++k)
        acc2 = fmaf(__shfl(hr, k), wreg[k], acc2);
    if (lane < F_OUT)
        h2b[(long)node * F_OUT + lane] = __float2bfloat16(acc2);
}

// ---- conv2 gather (bf16, MLP-4) + self + bias + log_softmax ----
__global__ __launch_bounds__(256) void k_conv2(
        const __hip_bfloat16* __restrict__ h2b, const int2* __restrict__ pairs,
        const int* __restrict__ off, const int* __restrict__ endp,
        const float* __restrict__ dinv, const float* __restrict__ b2,
        float* __restrict__ out, int n) {
    int lane = threadIdx.x & 63;
    int node = blockIdx.x * 4 + (threadIdx.x >> 6);
    if (node >= n) return;
    int s = off[node], e = endp[node];
    bool act = lane < F_OUT;
    float acc = 0.f;
    int j = s;
    while (j < e) {
        int cnt = e - j;
        if (cnt > 64) cnt = 64;
        int2 p = make_int2(0, 0);
        if (lane < cnt) p = pairs[j + lane];
        float pw = __int_as_float(p.y);
        int i = 0;
        for (; i + 4 <= cnt; i += 4) {
            int s0 = __shfl(p.x, i),     s1 = __shfl(p.x, i + 1);
            int s2 = __shfl(p.x, i + 2), s3 = __shfl(p.x, i + 3);
            float w0 = __shfl(pw, i),     w1 = __shfl(pw, i + 1);
            float w2 = __shfl(pw, i + 2), w3 = __shfl(pw, i + 3);
            if (act) {
                float v0 = __bfloat162float(h2b[(long)s0 * F_OUT + lane]);
                float v1 = __bfloat162float(h2b[(long)s1 * F_OUT + lane]);
                float v2 = __bfloat162float(h2b[(long)s2 * F_OUT + lane]);
                float v3 = __bfloat162float(h2b[(long)s3 * F_OUT + lane]);
                acc = fmaf(w0, v0, acc);
                acc = fmaf(w1, v1, acc);
                acc = fmaf(w2, v2, acc);
                acc = fmaf(w3, v3, acc);
            }
        }
        for (; i < cnt; ++i) {
            int sv = __shfl(p.x, i);
            float wv = __shfl(pw, i);
            if (act)
                acc = fmaf(wv, __bfloat162float(h2b[(long)sv * F_OUT + lane]), acc);
        }
        j += cnt;
    }
    float d = dinv[node];
    float v = -INFINITY;
    if (act) {
        float self = __bfloat162float(h2b[(long)node * F_OUT + lane]);
        v = d * acc + d * d * self + b2[lane];
    }
    float m = v;
    #pragma unroll
    for (int o = 32; o > 0; o >>= 1) m = fmaxf(m, __shfl_xor(m, o));
    float ex = act ? expf(v - m) : 0.f;
    float ssum = ex;
    #pragma unroll
    for (int o = 32; o > 0; o >>= 1) ssum += __shfl_xor(ssum, o);
    float lse = logf(ssum) + m;
    if (act) out[(long)node * F_OUT + lane] = v - lse;
}

extern "C" void kernel_launch(void* const* d_in, const int* in_sizes, int n_in,
                              void* d_out, int out_size, void* d_ws, size_t ws_size,
                              hipStream_t stream) {
    const float* x     = (const float*)d_in[0];
    const int*   ei    = (const int*)d_in[1];
    const float* gamma = (const float*)d_in[2];
    const float* beta  = (const float*)d_in[3];
    const float* rmean = (const float*)d_in[4];
    const float* rvar  = (const float*)d_in[5];
    const float* W1    = (const float*)d_in[6];
    const float* b1    = (const float*)d_in[7];
    const float* W2    = (const float*)d_in[8];
    const float* b2    = (const float*)d_in[9];
    float* out = (float*)d_out;

    int n = in_sizes[0] / F_IN;
    int E = in_sizes[1] / 2;
    const int* row = ei;       // edge_index[0] = source
    const int* col = ei + E;   // edge_index[1] = target

    // workspace: ints, dinv, pairs, h1b (bf16), h2b (bf16)
    int*   deg    = (int*)d_ws;
    int*   off    = deg + n;
    int*   fill   = off + n;
    float* dinv   = (float*)(fill + n);
    int*   cursor = (int*)(dinv + n);                 // 2 ints for alignment
    int2*  pairs  = (int2*)(cursor + 2);              // E pairs, 8B aligned
    __hip_bfloat16* h1b = (__hip_bfloat16*)(pairs + E);        // n*64 bf16
    __hip_bfloat16* h2b = h1b + (size_t)n * F_HID;             // n*40 bf16

    hipMemsetAsync(deg, 0, (size_t)n * sizeof(int), stream);
    hipMemsetAsync(cursor, 0, 2 * sizeof(int), stream);

    k_deg    <<<(E + 255) / 256, 256, 0, stream>>>(col, E, deg);
    k_offsets<<<(n + 255) / 256, 256, 0, stream>>>(deg, off, fill, dinv, cursor, n);
    k_edges  <<<(E + 255) / 256, 256, 0, stream>>>(row, col, dinv, fill, pairs, E);
    // after k_edges: fill[i] == off[i] + deg[i] == segment end

    k_gemm1<<<(n + 63) / 64, 64, 0, stream>>>(x, gamma, beta, rmean, rvar, W1, h1b, n);
    k_conv1<<<(n + 3) / 4, 256, 0, stream>>>(h1b, pairs, off, fill, dinv, b1, W2, h2b, n);
    k_conv2<<<(n + 3) / 4, 256, 0, stream>>>(h2b, pairs, off, fill, dinv, b2, out, n);
}

// Round 4
// 574.565 us; speedup vs baseline: 4.8387x; 1.0789x over previous
//
#include <hip/hip_runtime.h>
#include <hip/hip_bf16.h>
#include <math.h>

#define F_IN 128
#define F_HID 64
#define F_OUT 40
#define BN_EPS 1e-5f

__device__ __forceinline__ float bflo(unsigned u) { return __uint_as_float(u << 16); }
__device__ __forceinline__ float bfhi(unsigned u) { return __uint_as_float(u & 0xffff0000u); }

// ---- in-degree histogram (int atomics) ----
__global__ void k_deg(const int* __restrict__ col, int E, int* __restrict__ deg) {
    int e = blockIdx.x * blockDim.x + threadIdx.x;
    if (e < E) atomicAdd(deg + col[e], 1);
}

// ---- segment allocation via global cursor; also dinv = rsqrt(deg+1) ----
__global__ void k_offsets(const int* __restrict__ deg, int* __restrict__ off,
                          int* __restrict__ fill, float* __restrict__ dinv,
                          int* __restrict__ cursor, int n) {
    int i = blockIdx.x * blockDim.x + threadIdx.x;
    if (i >= n) return;
    int d = deg[i];
    int base = atomicAdd(cursor, d);
    off[i] = base;
    fill[i] = base;
    dinv[i] = rsqrtf((float)d + 1.0f);  // +1 self-loop
}

// ---- scatter edge payload {src, dinv[src]} into CSR slots ----
__global__ void k_edges(const int* __restrict__ row, const int* __restrict__ col,
                        const float* __restrict__ dinv, int* __restrict__ fill,
                        int2* __restrict__ pairs, int E) {
    int e = blockIdx.x * blockDim.x + threadIdx.x;
    if (e >= E) return;
    int r = row[e], c = col[e];
    int pos = atomicAdd(fill + c, 1);
    int2 p;
    p.x = r;
    p.y = __float_as_int(dinv[r]);
    pairs[pos] = p;
}

// ---- h1 = BN(x) @ W1, lane = node, W1 rows as uniform (scalar) operands ----
__global__ __launch_bounds__(64) void k_gemm1(
        const float* __restrict__ x, const float* __restrict__ gamma,
        const float* __restrict__ beta, const float* __restrict__ mean,
        const float* __restrict__ var, const float* __restrict__ W1,
        __hip_bfloat16* __restrict__ h1b, int n) {
    __shared__ float xl[64 * 129];              // pad 129 -> conflict-free reads
    __shared__ __align__(16) float bs[F_IN];
    __shared__ __align__(16) float bt[F_IN];
    int lane = threadIdx.x;
    for (int f = lane; f < F_IN; f += 64) {
        float s = rsqrtf(var[f] + BN_EPS) * gamma[f];
        bs[f] = s;
        bt[f] = beta[f] - mean[f] * s;
    }
    __syncthreads();
    int nb = blockIdx.x * 64;
    int tn = lane >> 5;
    int f4 = (lane & 31) * 4;
    for (int it = 0; it < 32; ++it) {
        int r = it * 2 + tn;
        int node = nb + r;
        float4 v = make_float4(0.f, 0.f, 0.f, 0.f);
        if (node < n) v = *(const float4*)(x + (long)node * F_IN + f4);
        float4 s4 = *(const float4*)(bs + f4);
        float4 t4 = *(const float4*)(bt + f4);
        int base = r * 129 + f4;
        xl[base + 0] = v.x * s4.x + t4.x;
        xl[base + 1] = v.y * s4.y + t4.y;
        xl[base + 2] = v.z * s4.z + t4.z;
        xl[base + 3] = v.w * s4.w + t4.w;
    }
    __syncthreads();
    float acc[F_HID];
    #pragma unroll
    for (int f = 0; f < F_HID; ++f) acc[f] = 0.f;
    for (int k = 0; k < F_IN; ++k) {
        float xv = xl[lane * 129 + k];
        const float* wr = W1 + k * F_HID;
        #pragma unroll
        for (int f = 0; f < F_HID; ++f) acc[f] = fmaf(xv, wr[f], acc[f]);
    }
    int node = nb + lane;
    if (node < n) {
        __hip_bfloat16* dst = h1b + (long)node * F_HID;
        #pragma unroll
        for (int f = 0; f < F_HID; f += 2) {
            __hip_bfloat162 pr;
            pr.x = __float2bfloat16(acc[f]);
            pr.y = __float2bfloat16(acc[f + 1]);
            *(__hip_bfloat162*)(dst + f) = pr;
        }
    }
}

// ---- conv1: pair-gather (2 edges/wave-load) + self + bias + relu + GEMM2 ----
// h1 row = 64 bf16 = 32 dwords. Lanes 0-31: edge i; lanes 32-63: edge i+1.
// Each lane owns feats {2q, 2q+1}. W2 in LDS.
__global__ __launch_bounds__(256) void k_conv1(
        const unsigned* __restrict__ h1u, const int2* __restrict__ pairs,
        const int* __restrict__ off, const int* __restrict__ endp,
        const float* __restrict__ dinv, const float* __restrict__ b1,
        const float* __restrict__ W2, __hip_bfloat16* __restrict__ h2b, int n) {
    __shared__ float sW[F_HID * F_OUT + 24];  // pad: lanes>=40 read junk, discarded
    for (int i = threadIdx.x; i < F_HID * F_OUT + 24; i += 256)
        sW[i] = (i < F_HID * F_OUT) ? W2[i] : 0.f;
    __syncthreads();
    int lane = threadIdx.x & 63;
    int node = blockIdx.x * 4 + (threadIdx.x >> 6);
    if (node >= n) return;
    int half = lane >> 5;   // which edge of the pair
    int q    = lane & 31;   // dword within row
    int s = off[node], e = endp[node];
    float a0 = 0.f, a1 = 0.f;
    int j = s;
    while (j < e) {
        int cnt = e - j; if (cnt > 64) cnt = 64;
        int2 p = make_int2(0, 0);
        if (lane < cnt) p = pairs[j + lane];   // one coalesced 8B load / chunk
        float pw = __int_as_float(p.y);
        for (int i = 0; i < cnt; i += 8) {
            // 8 edges, 4 loads/lane; idx >= cnt hits zeroed lanes (w=0, src=0)
            int  s0 = __shfl(p.x, i + 0 + half); float w0 = __shfl(pw, i + 0 + half);
            int  s1 = __shfl(p.x, i + 2 + half); float w1 = __shfl(pw, i + 2 + half);
            int  s2 = __shfl(p.x, i + 4 + half); float w2 = __shfl(pw, i + 4 + half);
            int  s3 = __shfl(p.x, i + 6 + half); float w3 = __shfl(pw, i + 6 + half);
            unsigned u0 = h1u[(long)s0 * 32 + q];
            unsigned u1 = h1u[(long)s1 * 32 + q];
            unsigned u2 = h1u[(long)s2 * 32 + q];
            unsigned u3 = h1u[(long)s3 * 32 + q];
            a0 = fmaf(w0, bflo(u0), a0); a1 = fmaf(w0, bfhi(u0), a1);
            a0 = fmaf(w1, bflo(u1), a0); a1 = fmaf(w1, bfhi(u1), a1);
            a0 = fmaf(w2, bflo(u2), a0); a1 = fmaf(w2, bfhi(u2), a1);
            a0 = fmaf(w3, bflo(u3), a0); a1 = fmaf(w3, bfhi(u3), a1);
        }
        j += cnt;
    }
    // combine the two edge-halves: both halves end with full sums
    a0 += __shfl_xor(a0, 32);
    a1 += __shfl_xor(a1, 32);
    float d = dinv[node];
    unsigned us = h1u[(long)node * 32 + q];
    float2 bb = ((const float2*)b1)[q];
    float hr0 = fmaxf(d * a0 + d * d * bflo(us) + bb.x, 0.f);
    float hr1 = fmaxf(d * a1 + d * d * bfhi(us) + bb.y, 0.f);
    // fused GEMM2: feature k lives in lane k>>1, component k&1
    float acc2 = 0.f;
    #pragma unroll
    for (int k = 0; k < F_HID; k += 2) {
        float e0 = __shfl(hr0, k >> 1);
        float e1 = __shfl(hr1, k >> 1);
        acc2 = fmaf(e0, sW[k * F_OUT + lane], acc2);
        acc2 = fmaf(e1, sW[(k + 1) * F_OUT + lane], acc2);
    }
    if (lane < F_OUT)
        h2b[(long)node * F_OUT + lane] = __float2bfloat16(acc2);
}

// ---- conv2: pair-gather (3 edges x 20 dwords) + self + bias + log_softmax ----
// h2 row = 40 bf16 = 20 dwords. Lane group third = lane/20 handles edge i+third.
__global__ __launch_bounds__(256) void k_conv2(
        const unsigned* __restrict__ h2u, const int2* __restrict__ pairs,
        const int* __restrict__ off, const int* __restrict__ endp,
        const float* __restrict__ dinv, const float* __restrict__ b2,
        float* __restrict__ out, int n) {
    int lane = threadIdx.x & 63;
    int node = blockIdx.x * 4 + (threadIdx.x >> 6);
    if (node >= n) return;
    int third = lane / 20;
    int q = lane - third * 20;          // 0..19 (lanes 60-63: 0..3, results unread)
    if (third > 2) third = 2;
    int s = off[node], e = endp[node];
    float a0 = 0.f, a1 = 0.f;
    int j = s;
    while (j < e) {
        int cnt = e - j; if (cnt > 60) cnt = 60;   // <=60 keeps shfl idx < 64
        int2 p = make_int2(0, 0);
        if (lane < cnt) p = pairs[j + lane];
        float pw = __int_as_float(p.y);
        for (int i = 0; i < cnt; i += 6) {
            // 6 edges, 2 loads/lane; idx >= cnt hits zeroed lanes
            int  s0 = __shfl(p.x, i + third);     float w0 = __shfl(pw, i + third);
            int  s1 = __shfl(p.x, i + 3 + third); float w1 = __shfl(pw, i + 3 + third);
            unsigned u0 = h2u[(long)s0 * 20 + q];
            unsigned u1 = h2u[(long)s1 * 20 + q];
            a0 = fmaf(w0, bflo(u0), a0); a1 = fmaf(w0, bfhi(u0), a1);
            a0 = fmaf(w1, bflo(u1), a0); a1 = fmaf(w1, bfhi(u1), a1);
        }
        j += cnt;
    }
    // combine thirds: total for dword q (valid for all lanes)
    float t0 = __shfl(a0, q) + __shfl(a0, q + 20) + __shfl(a0, q + 40);
    float t1 = __shfl(a1, q) + __shfl(a1, q + 20) + __shfl(a1, q + 40);
    float d = dinv[node];
    unsigned us = h2u[(long)node * 20 + q];
    float2 bb = ((const float2*)b2)[q];
    float v0 = d * t0 + d * d * bflo(us) + bb.x;
    float v1 = d * t1 + d * d * bfhi(us) + bb.y;
    bool canon = (lane < 20);           // one canonical copy of each feature pair
    float vm = canon ? fmaxf(v0, v1) : -INFINITY;
    #pragma unroll
    for (int o = 32; o > 0; o >>= 1) vm = fmaxf(vm, __shfl_xor(vm, o));
    float ex = canon ? (expf(v0 - vm) + expf(v1 - vm)) : 0.f;
    #pragma unroll
    for (int o = 32; o > 0; o >>= 1) ex += __shfl_xor(ex, o);
    float lse = logf(ex) + vm;
    if (canon) {
        float2 o2; o2.x = v0 - lse; o2.y = v1 - lse;
        ((float2*)(out + (long)node * F_OUT))[q] = o2;
    }
}

extern "C" void kernel_launch(void* const* d_in, const int* in_sizes, int n_in,
                              void* d_out, int out_size, void* d_ws, size_t ws_size,
                              hipStream_t stream) {
    const float* x     = (const float*)d_in[0];
    const int*   ei    = (const int*)d_in[1];
    const float* gamma = (const float*)d_in[2];
    const float* beta  = (const float*)d_in[3];
    const float* rmean = (const float*)d_in[4];
    const float* rvar  = (const float*)d_in[5];
    const float* W1    = (const float*)d_in[6];
    const float* b1    = (const float*)d_in[7];
    const float* W2    = (const float*)d_in[8];
    const float* b2    = (const float*)d_in[9];
    float* out = (float*)d_out;

    int n = in_sizes[0] / F_IN;
    int E = in_sizes[1] / 2;
    const int* row = ei;       // edge_index[0] = source
    const int* col = ei + E;   // edge_index[1] = target

    int*   deg    = (int*)d_ws;
    int*   off    = deg + n;
    int*   fill   = off + n;
    float* dinv   = (float*)(fill + n);
    int*   cursor = (int*)(dinv + n);                 // 2 ints (alignment)
    int2*  pairs  = (int2*)(cursor + 2);              // E pairs, 8B aligned
    __hip_bfloat16* h1b = (__hip_bfloat16*)(pairs + E);   // n*64 bf16 (128B rows)
    __hip_bfloat16* h2b = h1b + (size_t)n * F_HID;        // n*40 bf16 (80B rows)

    hipMemsetAsync(deg, 0, (size_t)n * sizeof(int), stream);
    hipMemsetAsync(cursor, 0, 2 * sizeof(int), stream);

    k_deg    <<<(E + 255) / 256, 256, 0, stream>>>(col, E, deg);
    k_offsets<<<(n + 255) / 256, 256, 0, stream>>>(deg, off, fill, dinv, cursor, n);
    k_edges  <<<(E + 255) / 256, 256, 0, stream>>>(row, col, dinv, fill, pairs, E);
    // after k_edges: fill[i] == off[i] + deg[i] == segment end

    k_gemm1<<<(n + 63) / 64, 64, 0, stream>>>(x, gamma, beta, rmean, rvar, W1, h1b, n);
    k_conv1<<<(n + 3) / 4, 256, 0, stream>>>((const unsigned*)h1b, pairs, off, fill,
                                             dinv, b1, W2, h2b, n);
    k_conv2<<<(n + 3) / 4, 256, 0, stream>>>((const unsigned*)h2b, pairs, off, fill,
                                             dinv, b2, out, n);
}

// Round 5
// 525.186 us; speedup vs baseline: 5.2936x; 1.0940x over previous
//
#include <hip/hip_runtime.h>
#include <hip/hip_bf16.h>
#include <math.h>

#define F_IN 128
#define F_HID 64
#define F_OUT 40
#define BN_EPS 1e-5f

__device__ __forceinline__ float bflo(unsigned u) { return __uint_as_float(u << 16); }
__device__ __forceinline__ float bfhi(unsigned u) { return __uint_as_float(u & 0xffff0000u); }

// ---- in-degree histogram (int atomics, scattered) ----
__global__ void k_deg(const int* __restrict__ col, int E, int* __restrict__ deg) {
    int e = blockIdx.x * blockDim.x + threadIdx.x;
    if (e < E) atomicAdd(deg + col[e], 1);
}

// ---- segment allocation: block-level scan, ONE cursor atomic per block ----
__global__ __launch_bounds__(256) void k_offsets(
        const int* __restrict__ deg, int* __restrict__ off,
        int* __restrict__ fill, float* __restrict__ dinv,
        int* __restrict__ cursor, int n) {
    int i = blockIdx.x * 256 + threadIdx.x;
    int lane = threadIdx.x & 63, wv = threadIdx.x >> 6;
    int d = (i < n) ? deg[i] : 0;
    int scan = d;                       // inclusive wave scan
    #pragma unroll
    for (int o = 1; o < 64; o <<= 1) {
        int t = __shfl_up(scan, o);
        if (lane >= o) scan += t;
    }
    __shared__ int wsum[4];
    if (lane == 63) wsum[wv] = scan;
    __syncthreads();
    if (threadIdx.x == 0) {
        int s0 = wsum[0], s1 = wsum[1], s2 = wsum[2], s3 = wsum[3];
        int base = atomicAdd(cursor, s0 + s1 + s2 + s3);
        wsum[0] = base; wsum[1] = base + s0;
        wsum[2] = base + s0 + s1; wsum[3] = base + s0 + s1 + s2;
    }
    __syncthreads();
    if (i < n) {
        int b = wsum[wv] + scan - d;    // exclusive position
        off[i] = b;
        fill[i] = b;
        dinv[i] = rsqrtf((float)d + 1.0f);  // +1 self-loop
    }
}

// ---- scatter edge payload {src, dinv[src]} into CSR slots ----
__global__ void k_edges(const int* __restrict__ row, const int* __restrict__ col,
                        const float* __restrict__ dinv, int* __restrict__ fill,
                        int2* __restrict__ pairs, int E) {
    int e = blockIdx.x * blockDim.x + threadIdx.x;
    if (e >= E) return;
    int r = row[e], c = col[e];
    int pos = atomicAdd(fill + c, 1);
    int2 p;
    p.x = r;
    p.y = __float_as_int(dinv[r]);
    pairs[pos] = p;
}

// ---- h1 = BN(x) @ W1; lane=node, W1 rows as uniform scalar operands ----
// Two K-phases of 64 feats each -> LDS 16.6 KB -> ~9 waves/CU (was 4).
__global__ __launch_bounds__(64) void k_gemm1(
        const float* __restrict__ x, const float* __restrict__ gamma,
        const float* __restrict__ beta, const float* __restrict__ mean,
        const float* __restrict__ var, const float* __restrict__ W1,
        __hip_bfloat16* __restrict__ h1b, int n) {
    __shared__ float xl[64 * 65];       // pad 65: (65*lane+k)%32=(lane+k)%32 -> 2-way, free
    int lane = threadIdx.x;
    int nb = blockIdx.x * 64;
    float acc[F_HID];
    #pragma unroll
    for (int f = 0; f < F_HID; ++f) acc[f] = 0.f;
    int f4 = (lane & 15) * 4;           // staging feat quad
    int tn = lane >> 4;                 // staging node offset
    for (int ph = 0; ph < 2; ++ph) {
        int fb = ph * 64;
        float4 vr = *(const float4*)(var + fb + f4);
        float4 gm = *(const float4*)(gamma + fb + f4);
        float4 be = *(const float4*)(beta + fb + f4);
        float4 mn = *(const float4*)(mean + fb + f4);
        float sx = rsqrtf(vr.x + BN_EPS) * gm.x, tx = be.x - mn.x * sx;
        float sy = rsqrtf(vr.y + BN_EPS) * gm.y, ty = be.y - mn.y * sy;
        float sz = rsqrtf(vr.z + BN_EPS) * gm.z, tz = be.z - mn.z * sz;
        float sw = rsqrtf(vr.w + BN_EPS) * gm.w, tw = be.w - mn.w * sw;
        if (ph) __syncthreads();        // xl reuse
        for (int it = 0; it < 16; ++it) {
            int r = it * 4 + tn;
            int node = nb + r;
            float4 v = make_float4(0.f, 0.f, 0.f, 0.f);
            if (node < n) v = *(const float4*)(x + (long)node * F_IN + fb + f4);
            int b = r * 65 + f4;
            xl[b + 0] = v.x * sx + tx;
            xl[b + 1] = v.y * sy + ty;
            xl[b + 2] = v.z * sz + tz;
            xl[b + 3] = v.w * sw + tw;
        }
        __syncthreads();
        for (int k = 0; k < 64; ++k) {
            float xv = xl[lane * 65 + k];
            const float* wr = W1 + (fb + k) * F_HID;   // uniform -> s_load
            #pragma unroll
            for (int f = 0; f < F_HID; ++f) acc[f] = fmaf(xv, wr[f], acc[f]);
        }
    }
    int node = nb + lane;
    if (node < n) {
        __hip_bfloat16* dst = h1b + (long)node * F_HID;
        #pragma unroll
        for (int f = 0; f < F_HID; f += 2) {
            __hip_bfloat162 pr;
            pr.x = __float2bfloat16(acc[f]);
            pr.y = __float2bfloat16(acc[f + 1]);
            *(__hip_bfloat162*)(dst + f) = pr;
        }
    }
}

// ---- conv1: octet gather (8 edges per dwordx4) + self + bias + relu + GEMM2 ----
// lane = (g=L>>3 edge slot, f=L&7 feat octet). One uint4 load = 8 rows x 16B.
__global__ __launch_bounds__(256) void k_conv1(
        const uint4* __restrict__ h1q, const int2* __restrict__ pairs,
        const int* __restrict__ off, const int* __restrict__ endp,
        const float* __restrict__ dinv, const float* __restrict__ b1,
        const float* __restrict__ W2, __hip_bfloat162* __restrict__ h2v, int n) {
    __shared__ float sW[F_HID * F_OUT + 24];
    for (int i = threadIdx.x; i < F_HID * F_OUT + 24; i += 256)
        sW[i] = (i < F_HID * F_OUT) ? W2[i] : 0.f;
    __syncthreads();
    int lane = threadIdx.x & 63;
    int node = blockIdx.x * 4 + (threadIdx.x >> 6);
    if (node >= n) return;
    int g = lane >> 3;
    int f = lane & 7;
    int s = off[node], e = endp[node];
    float a[8];
    #pragma unroll
    for (int q = 0; q < 8; ++q) a[q] = 0.f;
    int j = s;
    while (j < e) {
        int cnt = e - j; if (cnt > 64) cnt = 64;
        int2 p = make_int2(0, 0);
        if (lane < cnt) p = pairs[j + lane];     // one coalesced 8B load / chunk
        float pw = __int_as_float(p.y);
        for (int i = 0; i < cnt; i += 16) {      // 16 edges, 2 KB in flight
            int   sA = __shfl(p.x, i + g);      float wA = __shfl(pw, i + g);
            int   sB = __shfl(p.x, i + 8 + g);  float wB = __shfl(pw, i + 8 + g);
            uint4 uA = h1q[(long)sA * 8 + f];
            uint4 uB = h1q[(long)sB * 8 + f];
            a[0] = fmaf(wA, bflo(uA.x), a[0]);  a[1] = fmaf(wA, bfhi(uA.x), a[1]);
            a[2] = fmaf(wA, bflo(uA.y), a[2]);  a[3] = fmaf(wA, bfhi(uA.y), a[3]);
            a[4] = fmaf(wA, bflo(uA.z), a[4]);  a[5] = fmaf(wA, bfhi(uA.z), a[5]);
            a[6] = fmaf(wA, bflo(uA.w), a[6]);  a[7] = fmaf(wA, bfhi(uA.w), a[7]);
            a[0] = fmaf(wB, bflo(uB.x), a[0]);  a[1] = fmaf(wB, bfhi(uB.x), a[1]);
            a[2] = fmaf(wB, bflo(uB.y), a[2]);  a[3] = fmaf(wB, bfhi(uB.y), a[3]);
            a[4] = fmaf(wB, bflo(uB.z), a[4]);  a[5] = fmaf(wB, bfhi(uB.z), a[5]);
            a[6] = fmaf(wB, bflo(uB.w), a[6]);  a[7] = fmaf(wB, bfhi(uB.w), a[7]);
        }
        j += cnt;
    }
    // reduce over the 8 edge slots (xor on lane bits 3..5); all lanes end replicated
    #pragma unroll
    for (int q = 0; q < 8; ++q) {
        a[q] += __shfl_xor(a[q], 8);
        a[q] += __shfl_xor(a[q], 16);
        a[q] += __shfl_xor(a[q], 32);
    }
    float d = dinv[node], d2 = d * d;
    uint4 us = h1q[(long)node * 8 + f];
    float4 bb0 = *(const float4*)(b1 + 8 * f);
    float4 bb1 = *(const float4*)(b1 + 8 * f + 4);
    float h[8];
    h[0] = fmaxf(d * a[0] + d2 * bflo(us.x) + bb0.x, 0.f);
    h[1] = fmaxf(d * a[1] + d2 * bfhi(us.x) + bb0.y, 0.f);
    h[2] = fmaxf(d * a[2] + d2 * bflo(us.y) + bb0.z, 0.f);
    h[3] = fmaxf(d * a[3] + d2 * bfhi(us.y) + bb0.w, 0.f);
    h[4] = fmaxf(d * a[4] + d2 * bflo(us.z) + bb1.x, 0.f);
    h[5] = fmaxf(d * a[5] + d2 * bfhi(us.z) + bb1.y, 0.f);
    h[6] = fmaxf(d * a[6] + d2 * bflo(us.w) + bb1.z, 0.f);
    h[7] = fmaxf(d * a[7] + d2 * bfhi(us.w) + bb1.w, 0.f);
    // fused GEMM2: feat k lives at lane k>>3, reg k&7 (replicated over g)
    float acc2 = 0.f;
    #pragma unroll
    for (int k = 0; k < F_HID; ++k)
        acc2 = fmaf(__shfl(h[k & 7], k >> 3), sW[k * F_OUT + lane], acc2);
    float lo = __shfl(acc2, (2 * lane) & 63);
    float hi = __shfl(acc2, (2 * lane + 1) & 63);
    if (lane < 20) {
        __hip_bfloat162 pr;
        pr.x = __float2bfloat16(lo);
        pr.y = __float2bfloat16(hi);
        h2v[(long)node * 20 + lane] = pr;
    }
}

// ---- conv2: 10-lane gather (6 edges per uint2 load) + self + log_softmax ----
__global__ __launch_bounds__(256) void k_conv2(
        const uint2* __restrict__ h2d, const int2* __restrict__ pairs,
        const int* __restrict__ off, const int* __restrict__ endp,
        const float* __restrict__ dinv, const float* __restrict__ b2,
        float* __restrict__ out, int n) {
    int lane = threadIdx.x & 63;
    int node = blockIdx.x * 4 + (threadIdx.x >> 6);
    if (node >= n) return;
    int g = lane / 10;              // 0..6 (lanes 60-63: g=6, duplicate work)
    int f = lane - g * 10;          // 0..9
    int s = off[node], e = endp[node];
    float a0 = 0.f, a1 = 0.f, a2 = 0.f, a3 = 0.f;
    int j = s;
    while (j < e) {
        int cnt = e - j; if (cnt > 60) cnt = 60;
        int2 p = make_int2(0, 0);
        if (lane < cnt) p = pairs[j + lane];
        float pw = __int_as_float(p.y);
        for (int i = 0; i < cnt; i += 12) {      // 12 edges, 2 loads in flight
            int   sA = __shfl(p.x, i + g);      float wA = __shfl(pw, i + g);
            int   sB = __shfl(p.x, i + 6 + g);  float wB = __shfl(pw, i + 6 + g);
            uint2 uA = h2d[(long)sA * 10 + f];
            uint2 uB = h2d[(long)sB * 10 + f];
            a0 = fmaf(wA, bflo(uA.x), a0);  a1 = fmaf(wA, bfhi(uA.x), a1);
            a2 = fmaf(wA, bflo(uA.y), a2);  a3 = fmaf(wA, bfhi(uA.y), a3);
            a0 = fmaf(wB, bflo(uB.x), a0);  a1 = fmaf(wB, bfhi(uB.x), a1);
            a2 = fmaf(wB, bflo(uB.y), a2);  a3 = fmaf(wB, bfhi(uB.y), a3);
        }
        j += cnt;
    }
    // reduce over g=0..5 (lanes f, f+10, ..., f+50)
    float t0 = 0.f, t1 = 0.f, t2 = 0.f, t3 = 0.f;
    #pragma unroll
    for (int gg = 0; gg < 6; ++gg) {
        int src = f + 10 * gg;
        t0 += __shfl(a0, src);
        t1 += __shfl(a1, src);
        t2 += __shfl(a2, src);
        t3 += __shfl(a3, src);
    }
    float d = dinv[node], d2 = d * d;
    uint2 us = h2d[(long)node * 10 + f];
    float4 bb = *(const float4*)(b2 + 4 * f);
    float v0 = d * t0 + d2 * bflo(us.x) + bb.x;
    float v1 = d * t1 + d2 * bfhi(us.x) + bb.y;
    float v2 = d * t2 + d2 * bflo(us.y) + bb.z;
    float v3 = d * t3 + d2 * bfhi(us.y) + bb.w;
    float vm = fmaxf(fmaxf(v0, v1), fmaxf(v2, v3));
    #pragma unroll
    for (int o = 32; o > 0; o >>= 1) vm = fmaxf(vm, __shfl_xor(vm, o));
    float ex = (lane < 10) ? (expf(v0 - vm) + expf(v1 - vm) + expf(v2 - vm) + expf(v3 - vm)) : 0.f;
    #pragma unroll
    for (int o = 32; o > 0; o >>= 1) ex += __shfl_xor(ex, o);
    float lse = logf(ex) + vm;
    if (lane < 10) {
        float4 o4 = make_float4(v0 - lse, v1 - lse, v2 - lse, v3 - lse);
        *(float4*)(out + (long)node * F_OUT + 4 * f) = o4;
    }
}

extern "C" void kernel_launch(void* const* d_in, const int* in_sizes, int n_in,
                              void* d_out, int out_size, void* d_ws, size_t ws_size,
                              hipStream_t stream) {
    const float* x     = (const float*)d_in[0];
    const int*   ei    = (const int*)d_in[1];
    const float* gamma = (const float*)d_in[2];
    const float* beta  = (const float*)d_in[3];
    const float* rmean = (const float*)d_in[4];
    const float* rvar  = (const float*)d_in[5];
    const float* W1    = (const float*)d_in[6];
    const float* b1    = (const float*)d_in[7];
    const float* W2    = (const float*)d_in[8];
    const float* b2    = (const float*)d_in[9];
    float* out = (float*)d_out;

    int n = in_sizes[0] / F_IN;
    int E = in_sizes[1] / 2;
    const int* row = ei;       // edge_index[0] = source
    const int* col = ei + E;   // edge_index[1] = target

    int*   deg    = (int*)d_ws;
    int*   off    = deg + n;
    int*   fill   = off + n;
    float* dinv   = (float*)(fill + n);
    int*   cursor = (int*)(dinv + n);                 // 4 ints -> keep 16B alignment
    int2*  pairs  = (int2*)(cursor + 4);              // E pairs
    __hip_bfloat16* h1b = (__hip_bfloat16*)(pairs + E);   // n*64 bf16, 16B-aligned rows
    __hip_bfloat16* h2b = h1b + (size_t)n * F_HID;        // n*40 bf16, 8B-aligned rows

    hipMemsetAsync(deg, 0, (size_t)n * sizeof(int), stream);
    hipMemsetAsync(cursor, 0, 4 * sizeof(int), stream);

    k_deg    <<<(E + 255) / 256, 256, 0, stream>>>(col, E, deg);
    k_offsets<<<(n + 255) / 256, 256, 0, stream>>>(deg, off, fill, dinv, cursor, n);
    k_edges  <<<(E + 255) / 256, 256, 0, stream>>>(row, col, dinv, fill, pairs, E);
    // after k_edges: fill[i] == off[i] + deg[i] == segment end

    k_gemm1<<<(n + 63) / 64, 64, 0, stream>>>(x, gamma, beta, rmean, rvar, W1, h1b, n);
    k_conv1<<<(n + 3) / 4, 256, 0, stream>>>((const uint4*)h1b, pairs, off, fill,
                                             dinv, b1, W2, (__hip_bfloat162*)h2b, n);
    k_conv2<<<(n + 3) / 4, 256, 0, stream>>>((const uint2*)h2b, pairs, off, fill,
                                             dinv, b2, out, n);
}